// Round 1
// baseline (3202.538 us; speedup 1.0000x reference)
//
#include <hip/hip_runtime.h>
#include <math.h>

// Problem constants
constexpr int Bb = 64;    // batch
constexpr int Pp = 400;   // passage len
constexpr int Qq = 50;    // question len
constexpr int Ee = 300;   // embed dim
constexpr int Hh = 256;   // hidden
constexpr int H3 = 768;   // 3*H
constexpr int Dd = 512;   // 2*H

#define NEGC (-10000000.0f)
#define LOGTINY (-103.278929903f)   // log(float32(1e-45)) = log(2^-149)

__device__ __forceinline__ float allred(float v){
  #pragma unroll
  for (int off = 1; off < 64; off <<= 1) v += __shfl_xor(v, off);
  return v;
}
__device__ __forceinline__ float allmax(float v){
  #pragma unroll
  for (int off = 1; off < 64; off <<= 1) v = fmaxf(v, __shfl_xor(v, off));
  return v;
}
__device__ __forceinline__ float sigm(float x){ return 1.f / (1.f + expf(-x)); }

// ---------------------------------------------------------------------------
// Weight prep: WihT[g][d][e][h] (k-major for GEMM B-operand)
// ---------------------------------------------------------------------------
__global__ __launch_bounds__(256) void prep_wih(const float* __restrict__ pW,
                                                const float* __restrict__ qW,
                                                float* __restrict__ wihT){
  int idx = blockIdx.x * 256 + threadIdx.x;
  if (idx >= 2 * 2 * Ee * H3) return;
  int h = idx % H3; int r = idx / H3;
  int e = r % Ee; r /= Ee;
  int d = r & 1; int g = r >> 1;
  const float* W = g ? qW : pW;
  wihT[idx] = W[((size_t)d * H3 + h) * Ee + e];
}

// WhhT4[g][d][k4][j][r] : per-lane float4 of 4 consecutive k for column j
__global__ __launch_bounds__(256) void prep_whh(const float* __restrict__ pW,
                                                const float* __restrict__ qW,
                                                float* __restrict__ wt4){
  int idx = blockIdx.x * 256 + threadIdx.x;
  if (idx >= 2 * 2 * 64 * H3 * 4) return;
  int r = idx & 3; int t2 = idx >> 2;
  int j = t2 % H3; t2 /= H3;
  int k4 = t2 % 64; t2 /= 64;
  int d = t2 & 1; int g = t2 >> 1;
  const float* W = g ? qW : pW;
  wt4[idx] = W[((size_t)d * H3 + j) * Hh + k4 * 4 + r];
}

// ---------------------------------------------------------------------------
// xproj GEMM with fused embedding gather:
// out[d][b][t][h] = sum_e emb[tok[b,t]][e] * Wih[d][h][e] + bih[d][h]
// A: (B*T, 300) gathered rows of emb ; B: wihT (300, 1536) ; tile 64x64, BK=32
// ---------------------------------------------------------------------------
__global__ __launch_bounds__(256) void xproj_gemm(const int* __restrict__ tok,
                                                  const float* __restrict__ emb,
                                                  const float* __restrict__ wihT,
                                                  const float* __restrict__ bih,
                                                  float* __restrict__ xp, int T){
  __shared__ __align__(16) float As[64][33];
  __shared__ __align__(16) float Bs[32][68];
  int tid = threadIdx.x;
  int m0 = blockIdx.y * 64;
  int n0 = blockIdx.x * 64;
  int d = n0 / H3; int h0 = n0 % H3;
  const float* wT = wihT + (size_t)d * Ee * H3 + h0;

  int ar = tid >> 2;            // 0..63
  int ac = (tid & 3) * 8;       // 0,8,16,24
  const float* erow = emb + (size_t)tok[m0 + ar] * Ee;
  int bk = tid >> 3;            // 0..31
  int bc = (tid & 7) * 8;       // 0..56
  int ty = tid >> 4, tx = tid & 15;

  float acc[4][4] = {};
  for (int k0 = 0; k0 < Ee; k0 += 32){
    // A tile (gathered)
    #pragma unroll
    for (int u = 0; u < 8; u += 4){
      int k = k0 + ac + u;
      float4 v;
      if (k + 4 <= Ee) v = *(const float4*)(erow + k);
      else {
        v.x = (k     < Ee) ? erow[k]     : 0.f;
        v.y = (k + 1 < Ee) ? erow[k + 1] : 0.f;
        v.z = (k + 2 < Ee) ? erow[k + 2] : 0.f;
        v.w = (k + 3 < Ee) ? erow[k + 3] : 0.f;
      }
      As[ar][ac + u + 0] = v.x; As[ar][ac + u + 1] = v.y;
      As[ar][ac + u + 2] = v.z; As[ar][ac + u + 3] = v.w;
    }
    // B tile
    {
      int k = k0 + bk;
      const float* brow = wT + (size_t)k * H3;
      #pragma unroll
      for (int u = 0; u < 8; u += 4){
        float4 v = {0.f, 0.f, 0.f, 0.f};
        if (k < Ee) v = *(const float4*)(brow + bc + u);
        Bs[bk][bc + u + 0] = v.x; Bs[bk][bc + u + 1] = v.y;
        Bs[bk][bc + u + 2] = v.z; Bs[bk][bc + u + 3] = v.w;
      }
    }
    __syncthreads();
    #pragma unroll
    for (int k = 0; k < 32; ++k){
      float a0 = As[ty * 4 + 0][k];
      float a1 = As[ty * 4 + 1][k];
      float a2 = As[ty * 4 + 2][k];
      float a3 = As[ty * 4 + 3][k];
      float4 bv = *(const float4*)&Bs[k][tx * 4];
      acc[0][0] += a0 * bv.x; acc[0][1] += a0 * bv.y; acc[0][2] += a0 * bv.z; acc[0][3] += a0 * bv.w;
      acc[1][0] += a1 * bv.x; acc[1][1] += a1 * bv.y; acc[1][2] += a1 * bv.z; acc[1][3] += a1 * bv.w;
      acc[2][0] += a2 * bv.x; acc[2][1] += a2 * bv.y; acc[2][2] += a2 * bv.z; acc[2][3] += a2 * bv.w;
      acc[3][0] += a3 * bv.x; acc[3][1] += a3 * bv.y; acc[3][2] += a3 * bv.z; acc[3][3] += a3 * bv.w;
    }
    __syncthreads();
  }
  // epilogue: add bias, scatter rows (b,t)
  int hb = h0 + tx * 4;
  float4 bias = *(const float4*)(bih + d * H3 + hb);
  #pragma unroll
  for (int i = 0; i < 4; ++i){
    int m = m0 + ty * 4 + i;
    int bI = m / T, tI = m % T;
    size_t off = (((size_t)d * Bb + bI) * T + tI) * H3 + hb;
    float4 o;
    o.x = acc[i][0] + bias.x; o.y = acc[i][1] + bias.y;
    o.z = acc[i][2] + bias.z; o.w = acc[i][3] + bias.w;
    *(float4*)(xp + off) = o;
  }
}

// ---------------------------------------------------------------------------
// Bidirectional GRU recurrence. One WG per (direction, batch-pair).
// WGs 0..63 : passage (T=400) ; WGs 64..127 : question (T=50).
// 768 threads: thread j computes hp[j] = h . WhhT4[:,j] for 2 batches.
// ---------------------------------------------------------------------------
__global__ __launch_bounds__(768) void gru_kernel(const int* __restrict__ ptok,
                                                  const int* __restrict__ qtok,
                                                  const float* __restrict__ xp_p,
                                                  const float* __restrict__ xp_q,
                                                  const float* __restrict__ wt4_p,
                                                  const float* __restrict__ wt4_q,
                                                  const float* __restrict__ pbhh,
                                                  const float* __restrict__ qbhh,
                                                  float* __restrict__ Hp,
                                                  float* __restrict__ Hq){
  int wg = blockIdx.x;
  bool isp = wg < 64;
  int lw = isp ? wg : wg - 64;
  int d = lw & 1, bpair = lw >> 1;
  int T = isp ? Pp : Qq;
  const int* tok = isp ? ptok : qtok;
  const float* xp = (isp ? xp_p : xp_q) + (size_t)d * Bb * T * H3;
  const float4* w4 = (const float4*)((isp ? wt4_p : wt4_q) + (size_t)d * 64 * H3 * 4);
  const float* bhh = (isp ? pbhh : qbhh) + d * H3;
  float* Hout = isp ? Hp : Hq;

  __shared__ __align__(16) float hs[2][Hh];
  __shared__ __align__(16) float hpv[2][H3];
  __shared__ __align__(16) float xs[2][H3];
  int tid = threadIdx.x;
  if (tid < 512) hs[tid >> 8][tid & 255] = 0.f;
  float bh = bhh[tid];
  int b0 = bpair * 2, b1 = bpair * 2 + 1;
  const float* x0 = xp + (size_t)b0 * T * H3;
  const float* x1 = xp + (size_t)b1 * T * H3;
  __syncthreads();

  for (int s = 0; s < T; ++s){
    int t = d ? (T - 1 - s) : s;
    // prefetch x-projection for this step (independent of h)
    float xt0 = x0[(size_t)t * H3 + tid];
    float xt1 = x1[(size_t)t * H3 + tid];
    xs[0][tid] = xt0; xs[1][tid] = xt1;
    float acc0 = bh, acc1 = bh;
    #pragma unroll 4
    for (int k4 = 0; k4 < 64; ++k4){
      float4 w  = w4[(size_t)k4 * H3 + tid];
      float4 h0 = *(const float4*)&hs[0][k4 * 4];
      float4 h1 = *(const float4*)&hs[1][k4 * 4];
      acc0 += w.x * h0.x + w.y * h0.y + w.z * h0.z + w.w * h0.w;
      acc1 += w.x * h1.x + w.y * h1.y + w.z * h1.z + w.w * h1.w;
    }
    hpv[0][tid] = acc0; hpv[1][tid] = acc1;
    __syncthreads();
    if (tid < 512){
      int bb = tid >> 8, j = tid & 255;
      int b = bb ? b1 : b0;
      float r = sigm(xs[bb][j] + hpv[bb][j]);
      float z = sigm(xs[bb][Hh + j] + hpv[bb][Hh + j]);
      float n = tanhf(xs[bb][2 * Hh + j] + r * hpv[bb][2 * Hh + j]);
      float hprev = hs[bb][j];
      float hn = (1.f - z) * n + z * hprev;
      float m = (tok[b * T + t] != 0) ? 1.f : 0.f;
      float hm = m * hn + (1.f - m) * hprev;
      hs[bb][j] = hm;
      Hout[((size_t)b * T + t) * Dd + d * Hh + j] = hm * m;
    }
    __syncthreads();
  }
}

// ---------------------------------------------------------------------------
// Attention + logits. One WG per (batch, p-chunk of 100). 8 waves, wave = one p.
// combined @ w decomposes: logit = Hp.w1 + wavg.w2 + (Hp*wavg).w3 + bias
// Writes start_logits -> out[0:25600], end_logits -> out[25600:51200]
// ---------------------------------------------------------------------------
__global__ __launch_bounds__(512) void attn_kernel(const float* __restrict__ Hp,
                                                   const float* __restrict__ Hq,
                                                   const int* __restrict__ ptok,
                                                   const int* __restrict__ qtok,
                                                   const float* __restrict__ start_w,
                                                   const float* __restrict__ sbp,
                                                   const float* __restrict__ end_w,
                                                   const float* __restrict__ ebp,
                                                   float* __restrict__ out){
  extern __shared__ __align__(16) float lds[];
  float* hqs = lds;               // 50*512
  float* s2s = hqs + Qq * Dd;     // 64
  float* qms = s2s + 64;          // 64
  float* scw = qms + 64;          // 8*64
  float* aw  = scw + 512;         // 8*64

  int b = blockIdx.y, pc = blockIdx.x;
  int tid = threadIdx.x, wid = tid >> 6, lane = tid & 63;
  float sb = sbp[0], eb = ebp[0];

  float w1r[8], w2r[8], w3r[8], e1r[8], e2r[8], e3r[8];
  #pragma unroll
  for (int i = 0; i < 8; ++i){
    int c = lane * 8 + i;
    w1r[i] = start_w[c]; w2r[i] = start_w[Dd + c]; w3r[i] = start_w[2 * Dd + c];
    e1r[i] = end_w[c];   e2r[i] = end_w[Dd + c];   e3r[i] = end_w[2 * Dd + c];
  }
  for (int idx = tid; idx < Qq * Dd; idx += 512) hqs[idx] = Hq[(size_t)b * Qq * Dd + idx];
  __syncthreads();

  // per-q: s2 = Hq.w2 and question mask
  for (int q = wid; q < Qq; q += 8){
    float part = 0.f;
    const float* hq = hqs + q * Dd + lane * 8;
    #pragma unroll
    for (int i = 0; i < 8; ++i) part += hq[i] * w2r[i];
    part = allred(part);
    if (lane == 0){
      s2s[q] = part;
      qms[q] = (qtok[b * Qq + q] != 0) ? 1.f : 0.f;
    }
  }
  __syncthreads();

  for (int p = pc * 100 + wid; p < pc * 100 + 100; p += 8){
    const float* hprow = Hp + ((size_t)b * Pp + p) * Dd + lane * 8;
    float4 hv0 = *(const float4*)hprow;
    float4 hv1 = *(const float4*)(hprow + 4);
    float hpc[8] = {hv0.x, hv0.y, hv0.z, hv0.w, hv1.x, hv1.y, hv1.z, hv1.w};
    float hw3[8], he3[8];
    float s1 = 0.f, ed = 0.f;
    #pragma unroll
    for (int i = 0; i < 8; ++i){
      hw3[i] = hpc[i] * w3r[i];
      he3[i] = hpc[i] * e3r[i];
      s1 += hpc[i] * w1r[i];
      ed += hpc[i] * e1r[i];
    }
    #pragma unroll
    for (int off = 1; off < 64; off <<= 1){
      s1 += __shfl_xor(s1, off);
      ed += __shfl_xor(ed, off);
    }
    // scores
    for (int q = 0; q < Qq; ++q){
      const float4* hq4 = (const float4*)(hqs + q * Dd + lane * 8);
      float4 a0 = hq4[0], a1 = hq4[1];
      float dot = hw3[0] * a0.x + hw3[1] * a0.y + hw3[2] * a0.z + hw3[3] * a0.w
                + hw3[4] * a1.x + hw3[5] * a1.y + hw3[6] * a1.z + hw3[7] * a1.w;
      dot = allred(dot);
      if (lane == 0) scw[wid * 64 + q] = (s1 + s2s[q] + dot + sb) * qms[q];
    }
    // masked softmax over q (exactly mirrors reference semantics)
    float v = (lane < Qq) ? scw[wid * 64 + lane] : -1e30f;
    float M = allmax(v);
    float ev = (lane < Qq) ? expf(v - M) : 0.f;
    float S = allred(ev);
    float am = (lane < Qq) ? (ev / S) * qms[lane] : 0.f;
    float Sm = allred(am);
    float af = am / (Sm + 1e-13f);
    if (lane < Qq) aw[wid * 64 + lane] = af;
    // wavg over the lane's 8 channels
    float wv[8] = {0.f, 0.f, 0.f, 0.f, 0.f, 0.f, 0.f, 0.f};
    for (int q = 0; q < Qq; ++q){
      float aq = aw[wid * 64 + q];
      const float4* hq4 = (const float4*)(hqs + q * Dd + lane * 8);
      float4 a0 = hq4[0], a1 = hq4[1];
      wv[0] += aq * a0.x; wv[1] += aq * a0.y; wv[2] += aq * a0.z; wv[3] += aq * a0.w;
      wv[4] += aq * a1.x; wv[5] += aq * a1.y; wv[6] += aq * a1.z; wv[7] += aq * a1.w;
    }
    float acc2 = 0.f, acc3 = 0.f, acc4 = 0.f, acc5 = 0.f;
    #pragma unroll
    for (int i = 0; i < 8; ++i){
      acc2 += wv[i] * w2r[i];
      acc3 += hw3[i] * wv[i];
      acc4 += wv[i] * e2r[i];
      acc5 += he3[i] * wv[i];
    }
    #pragma unroll
    for (int off = 1; off < 64; off <<= 1){
      acc2 += __shfl_xor(acc2, off);
      acc3 += __shfl_xor(acc3, off);
      acc4 += __shfl_xor(acc4, off);
      acc5 += __shfl_xor(acc5, off);
    }
    if (lane == 0){
      bool pm = (ptok[b * Pp + p] != 0);
      out[(size_t)b * Pp + p]                = pm ? (s1 + acc2 + acc3 + sb) : NEGC;
      out[(size_t)Bb * Pp + (size_t)b * Pp + p] = pm ? (ed + acc4 + acc5 + eb) : NEGC;
    }
  }
}

// ---------------------------------------------------------------------------
// log_softmax over p. One WG per (batch, start/end).
// ---------------------------------------------------------------------------
__global__ __launch_bounds__(512) void lsm_kernel(const int* __restrict__ ptok,
                                                  float* __restrict__ out){
  int b = blockIdx.x >> 1, sel = blockIdx.x & 1;
  const float* lg = out + (size_t)sel * Bb * Pp + (size_t)b * Pp;
  float* o = out + (size_t)(2 + sel) * Bb * Pp + (size_t)b * Pp;
  int tid = threadIdx.x;
  __shared__ float red1[8];
  __shared__ float red2[8];
  float x = -1e30f;
  if (tid < Pp) x = lg[tid] + ((ptok[b * Pp + tid] != 0) ? 0.f : LOGTINY);
  float m = allmax(x);
  if ((tid & 63) == 0) red1[tid >> 6] = m;
  __syncthreads();
  float M = red1[0];
  #pragma unroll
  for (int i = 1; i < 8; ++i) M = fmaxf(M, red1[i]);
  float e = (tid < Pp) ? expf(x - M) : 0.f;
  float s = allred(e);
  if ((tid & 63) == 0) red2[tid >> 6] = s;
  __syncthreads();
  float S = 0.f;
  #pragma unroll
  for (int i = 0; i < 8; ++i) S += red2[i];
  if (tid < Pp) o[tid] = (x - M) - logf(S);
}

// ---------------------------------------------------------------------------
extern "C" void kernel_launch(void* const* d_in, const int* in_sizes, int n_in,
                              void* d_out, int out_size, void* d_ws, size_t ws_size,
                              hipStream_t stream){
  const int*   passage  = (const int*)d_in[0];
  const int*   question = (const int*)d_in[1];
  const float* emb      = (const float*)d_in[2];
  const float* pW_ih    = (const float*)d_in[3];
  // pW_hh = d_in[4]
  const float* pb_ih    = (const float*)d_in[5];
  const float* pb_hh    = (const float*)d_in[6];
  const float* qW_ih    = (const float*)d_in[7];
  // qW_hh = d_in[8]
  const float* qb_ih    = (const float*)d_in[9];
  const float* qb_hh    = (const float*)d_in[10];
  const float* start_w  = (const float*)d_in[11];
  const float* start_b  = (const float*)d_in[12];
  const float* end_w    = (const float*)d_in[13];
  const float* end_b    = (const float*)d_in[14];
  const float* pW_hh    = (const float*)d_in[4];
  const float* qW_hh    = (const float*)d_in[8];
  float* out = (float*)d_out;

  // workspace layout (floats)
  float* ws   = (float*)d_ws;
  float* wihT = ws;                 //   921600 : [g][d][e][h]
  float* wt4  = ws + 921600;        //   786432 : [g][d][k4][j][4]
  float* xpp  = ws + 1708032;       // 39321600 : [d][b][t][768]
  float* xpq  = ws + 41029632;      //  4915200
  float* Hp   = ws + 45944832;      // 13107200 : [b][t][512]
  float* Hq   = ws + 59052032;      //  1638400
  // total 60,690,432 floats = 242.8 MB

  hipLaunchKernelGGL(prep_wih, dim3(3600), dim3(256), 0, stream, pW_ih, qW_ih, wihT);
  hipLaunchKernelGGL(prep_whh, dim3(3072), dim3(256), 0, stream, pW_hh, qW_hh, wt4);
  hipLaunchKernelGGL(xproj_gemm, dim3(24, 400), dim3(256), 0, stream,
                     passage, emb, wihT, pb_ih, xpp, Pp);
  hipLaunchKernelGGL(xproj_gemm, dim3(24, 50), dim3(256), 0, stream,
                     question, emb, wihT + 460800, qb_ih, xpq, Qq);
  hipLaunchKernelGGL(gru_kernel, dim3(128), dim3(768), 0, stream,
                     passage, question, xpp, xpq, wt4, wt4 + 393216, pb_hh, qb_hh, Hp, Hq);
  size_t attn_lds = (size_t)(Qq * Dd + 64 + 64 + 512 + 512) * sizeof(float);
  hipLaunchKernelGGL(attn_kernel, dim3(4, 64), dim3(512), attn_lds, stream,
                     Hp, Hq, passage, question, start_w, start_b, end_w, end_b, out);
  hipLaunchKernelGGL(lsm_kernel, dim3(128), dim3(512), 0, stream, passage, out);
}

// Round 2
// 1579.946 us; speedup vs baseline: 2.0270x; 2.0270x over previous
//
#include <hip/hip_runtime.h>
#include <math.h>

// Problem constants
constexpr int Bb = 64;    // batch
constexpr int Pp = 400;   // passage len
constexpr int Qq = 50;    // question len
constexpr int Ee = 300;   // embed dim
constexpr int Hh = 256;   // hidden
constexpr int H3 = 768;   // 3*H
constexpr int Dd = 512;   // 2*H

#define NEGC (-10000000.0f)
#define LOGTINY (-103.278929903f)   // log(float32(1e-45)) = log(2^-149)

typedef _Float16 h2 __attribute__((ext_vector_type(2)));

__device__ __forceinline__ float allred(float v){
  #pragma unroll
  for (int off = 1; off < 64; off <<= 1) v += __shfl_xor(v, off);
  return v;
}
__device__ __forceinline__ float allmax(float v){
  #pragma unroll
  for (int off = 1; off < 64; off <<= 1) v = fmaxf(v, __shfl_xor(v, off));
  return v;
}
__device__ __forceinline__ float sigm(float x){ return 1.f / (1.f + expf(-x)); }

__device__ __forceinline__ float dot2f(unsigned a, unsigned b, float c){
#if __has_builtin(__builtin_amdgcn_fdot2)
  return __builtin_amdgcn_fdot2(__builtin_bit_cast(h2, a), __builtin_bit_cast(h2, b), c, false);
#else
  h2 x = __builtin_bit_cast(h2, a), y = __builtin_bit_cast(h2, b);
  return c + (float)x[0] * (float)y[0] + (float)x[1] * (float)y[1];
#endif
}

// ---------------------------------------------------------------------------
// Weight prep: WihT[g][d][e][h] (k-major for GEMM B-operand)
// ---------------------------------------------------------------------------
__global__ __launch_bounds__(256) void prep_wih(const float* __restrict__ pW,
                                                const float* __restrict__ qW,
                                                float* __restrict__ wihT){
  int idx = blockIdx.x * 256 + threadIdx.x;
  if (idx >= 2 * 2 * Ee * H3) return;
  int h = idx % H3; int r = idx / H3;
  int e = r % Ee; r /= Ee;
  int d = r & 1; int g = r >> 1;
  const float* W = g ? qW : pW;
  wihT[idx] = W[((size_t)d * H3 + h) * Ee + e];
}

// Pack Whh to fp16 pairs, laid out so the GRU kernel's uint4 loads coalesce:
// w16[ (((g*2+d)*32 + q)*768 + j)*4 + c ] = pack(W[d][j][2p], W[d][j][2p+1]),
// with pair p = 4q + c  (p in [0,128): covers h[2p], h[2p+1]).
__global__ __launch_bounds__(256) void prep_w16(const float* __restrict__ pW,
                                                const float* __restrict__ qW,
                                                unsigned* __restrict__ w16){
  int idx = blockIdx.x * 256 + threadIdx.x;   // pair id
  if (idx >= 2 * 2 * 128 * H3) return;
  int j = idx % H3; int r = idx / H3;
  int p = r % 128; r /= 128;
  int d = r & 1; int g = r >> 1;
  const float* W = g ? qW : pW;
  float w0 = W[((size_t)d * H3 + j) * Hh + 2 * p];
  float w1 = W[((size_t)d * H3 + j) * Hh + 2 * p + 1];
  _Float16 a = (_Float16)w0, b = (_Float16)w1;
  unsigned short ua, ub;
  __builtin_memcpy(&ua, &a, 2); __builtin_memcpy(&ub, &b, 2);
  unsigned out = (unsigned)ua | ((unsigned)ub << 16);
  w16[(((size_t)(g * 2 + d) * 32 + (p >> 2)) * H3 + j) * 4 + (p & 3)] = out;
}

// ---------------------------------------------------------------------------
// xproj GEMM with fused embedding gather (fp32, unchanged this round)
// ---------------------------------------------------------------------------
__global__ __launch_bounds__(256) void xproj_gemm(const int* __restrict__ tok,
                                                  const float* __restrict__ emb,
                                                  const float* __restrict__ wihT,
                                                  const float* __restrict__ bih,
                                                  float* __restrict__ xp, int T){
  __shared__ __align__(16) float As[64][33];
  __shared__ __align__(16) float Bs[32][68];
  int tid = threadIdx.x;
  int m0 = blockIdx.y * 64;
  int n0 = blockIdx.x * 64;
  int d = n0 / H3; int h0 = n0 % H3;
  const float* wT = wihT + (size_t)d * Ee * H3 + h0;

  int ar = tid >> 2;            // 0..63
  int ac = (tid & 3) * 8;       // 0,8,16,24
  const float* erow = emb + (size_t)tok[m0 + ar] * Ee;
  int bk = tid >> 3;            // 0..31
  int bc = (tid & 7) * 8;       // 0..56
  int ty = tid >> 4, tx = tid & 15;

  float acc[4][4] = {};
  for (int k0 = 0; k0 < Ee; k0 += 32){
    #pragma unroll
    for (int u = 0; u < 8; u += 4){
      int k = k0 + ac + u;
      float4 v;
      if (k + 4 <= Ee) v = *(const float4*)(erow + k);
      else {
        v.x = (k     < Ee) ? erow[k]     : 0.f;
        v.y = (k + 1 < Ee) ? erow[k + 1] : 0.f;
        v.z = (k + 2 < Ee) ? erow[k + 2] : 0.f;
        v.w = (k + 3 < Ee) ? erow[k + 3] : 0.f;
      }
      As[ar][ac + u + 0] = v.x; As[ar][ac + u + 1] = v.y;
      As[ar][ac + u + 2] = v.z; As[ar][ac + u + 3] = v.w;
    }
    {
      int k = k0 + bk;
      const float* brow = wT + (size_t)k * H3;
      #pragma unroll
      for (int u = 0; u < 8; u += 4){
        float4 v = {0.f, 0.f, 0.f, 0.f};
        if (k < Ee) v = *(const float4*)(brow + bc + u);
        Bs[bk][bc + u + 0] = v.x; Bs[bk][bc + u + 1] = v.y;
        Bs[bk][bc + u + 2] = v.z; Bs[bk][bc + u + 3] = v.w;
      }
    }
    __syncthreads();
    #pragma unroll
    for (int k = 0; k < 32; ++k){
      float a0 = As[ty * 4 + 0][k];
      float a1 = As[ty * 4 + 1][k];
      float a2 = As[ty * 4 + 2][k];
      float a3 = As[ty * 4 + 3][k];
      float4 bv = *(const float4*)&Bs[k][tx * 4];
      acc[0][0] += a0 * bv.x; acc[0][1] += a0 * bv.y; acc[0][2] += a0 * bv.z; acc[0][3] += a0 * bv.w;
      acc[1][0] += a1 * bv.x; acc[1][1] += a1 * bv.y; acc[1][2] += a1 * bv.z; acc[1][3] += a1 * bv.w;
      acc[2][0] += a2 * bv.x; acc[2][1] += a2 * bv.y; acc[2][2] += a2 * bv.z; acc[2][3] += a2 * bv.w;
      acc[3][0] += a3 * bv.x; acc[3][1] += a3 * bv.y; acc[3][2] += a3 * bv.z; acc[3][3] += a3 * bv.w;
    }
    __syncthreads();
  }
  int hb = h0 + tx * 4;
  float4 bias = *(const float4*)(bih + d * H3 + hb);
  #pragma unroll
  for (int i = 0; i < 4; ++i){
    int m = m0 + ty * 4 + i;
    int bI = m / T, tI = m % T;
    size_t off = (((size_t)d * Bb + bI) * T + tI) * H3 + hb;
    float4 o;
    o.x = acc[i][0] + bias.x; o.y = acc[i][1] + bias.y;
    o.z = acc[i][2] + bias.z; o.w = acc[i][3] + bias.w;
    *(float4*)(xp + off) = o;
  }
}

// ---------------------------------------------------------------------------
// Register-resident GRU. One WG per (seq-kind, dir, batch): 256 WGs x 768 thr.
// Thread j holds Whh row j as 128 packed fp16-pair VGPRs (loaded once).
// Per step: h (fp32 in LDS) -> packed fp16 pairs in 2 VGPRs/lane ->
// v_readlane broadcast + v_dot2_f32_f16 accumulate. Gates fp32 on thr<256.
// ---------------------------------------------------------------------------
__global__ __launch_bounds__(768) void gru_kernel(const int* __restrict__ ptok,
                                                  const int* __restrict__ qtok,
                                                  const float* __restrict__ xpp,
                                                  const float* __restrict__ xpq,
                                                  const unsigned* __restrict__ w16,
                                                  const float* __restrict__ pbhh,
                                                  const float* __restrict__ qbhh,
                                                  float* __restrict__ Hp,
                                                  float* __restrict__ Hq){
  int wg = blockIdx.x;
  bool isp = wg < 128;
  int lw = isp ? wg : wg - 128;
  int d = lw & 1, b = lw >> 1;
  int T = isp ? Pp : Qq;
  const int* tok = (isp ? ptok : qtok) + b * T;
  const float* xrow = (isp ? xpp : xpq) + ((size_t)d * Bb + b) * T * H3;
  int gd = (isp ? 0 : 2) + d;
  const float* bhh = (isp ? pbhh : qbhh) + d * H3;
  float* Hout = (isp ? Hp : Hq) + (size_t)b * T * Dd + d * Hh;

  __shared__ float hs[Hh];
  __shared__ float us[2 * Hh];
  __shared__ float hnv[Hh];
  __shared__ float xnv[Hh];

  int j = threadIdx.x;
  unsigned w[128];
  {
    const uint4* wq = (const uint4*)w16 + (size_t)gd * 32 * H3;
    #pragma unroll
    for (int q = 0; q < 32; ++q){
      uint4 v = wq[q * H3 + j];
      w[4 * q + 0] = v.x; w[4 * q + 1] = v.y; w[4 * q + 2] = v.z; w[4 * q + 3] = v.w;
    }
  }
  float bh = bhh[j];
  float h_old = 0.f;
  if (j < Hh) hs[j] = 0.f;
  __syncthreads();

  int lane = j & 63;
  float pre = xrow[(size_t)(d ? (T - 1) : 0) * H3 + j];

  for (int s = 0; s < T; ++s){
    int t = d ? (T - 1 - s) : s;
    float xt = pre;
    if (s + 1 < T){
      int tn = d ? (T - 2 - s) : (s + 1);
      pre = xrow[(size_t)tn * H3 + j];
    }
    // pack h into per-lane fp16 pairs (identical across all waves)
    float2 p0 = *(const float2*)&hs[2 * lane];
    float2 p1 = *(const float2*)&hs[128 + 2 * lane];
    h2 hh0 = { (_Float16)p0.x, (_Float16)p0.y };
    h2 hh1 = { (_Float16)p1.x, (_Float16)p1.y };
    unsigned vh0 = __builtin_bit_cast(unsigned, hh0);
    unsigned vh1 = __builtin_bit_cast(unsigned, hh1);

    float acc0 = bh, acc1 = 0.f;
    #pragma unroll
    for (int q = 0; q < 32; ++q){
      #define RL(p) ((unsigned)__builtin_amdgcn_readlane((int)(((p) < 64) ? vh0 : vh1), (p) & 63))
      acc0 = dot2f(w[4 * q + 0], RL(4 * q + 0), acc0);
      acc1 = dot2f(w[4 * q + 1], RL(4 * q + 1), acc1);
      acc0 = dot2f(w[4 * q + 2], RL(4 * q + 2), acc0);
      acc1 = dot2f(w[4 * q + 3], RL(4 * q + 3), acc1);
      #undef RL
    }
    float acc = acc0 + acc1;
    if (j < 2 * Hh) us[j] = xt + acc;
    else { hnv[j - 2 * Hh] = acc; xnv[j - 2 * Hh] = xt; }
    __syncthreads();
    if (j < Hh){
      float r = sigm(us[j]);
      float z = sigm(us[Hh + j]);
      float n = tanhf(xnv[j] + r * hnv[j]);
      float hnew = (1.f - z) * n + z * h_old;
      float m = (tok[t] != 0) ? 1.f : 0.f;
      float hm = m * hnew + (1.f - m) * h_old;
      h_old = hm;
      hs[j] = hm;
      Hout[(size_t)t * Dd + j] = hm * m;
    }
    __syncthreads();
  }
}

// ---------------------------------------------------------------------------
// Attention + logits (unchanged)
// ---------------------------------------------------------------------------
__global__ __launch_bounds__(512) void attn_kernel(const float* __restrict__ Hp,
                                                   const float* __restrict__ Hq,
                                                   const int* __restrict__ ptok,
                                                   const int* __restrict__ qtok,
                                                   const float* __restrict__ start_w,
                                                   const float* __restrict__ sbp,
                                                   const float* __restrict__ end_w,
                                                   const float* __restrict__ ebp,
                                                   float* __restrict__ out){
  extern __shared__ __align__(16) float lds[];
  float* hqs = lds;               // 50*512
  float* s2s = hqs + Qq * Dd;     // 64
  float* qms = s2s + 64;          // 64
  float* scw = qms + 64;          // 8*64
  float* aw  = scw + 512;         // 8*64

  int b = blockIdx.y, pc = blockIdx.x;
  int tid = threadIdx.x, wid = tid >> 6, lane = tid & 63;
  float sb = sbp[0], eb = ebp[0];

  float w1r[8], w2r[8], w3r[8], e1r[8], e2r[8], e3r[8];
  #pragma unroll
  for (int i = 0; i < 8; ++i){
    int c = lane * 8 + i;
    w1r[i] = start_w[c]; w2r[i] = start_w[Dd + c]; w3r[i] = start_w[2 * Dd + c];
    e1r[i] = end_w[c];   e2r[i] = end_w[Dd + c];   e3r[i] = end_w[2 * Dd + c];
  }
  for (int idx = tid; idx < Qq * Dd; idx += 512) hqs[idx] = Hq[(size_t)b * Qq * Dd + idx];
  __syncthreads();

  for (int q = wid; q < Qq; q += 8){
    float part = 0.f;
    const float* hq = hqs + q * Dd + lane * 8;
    #pragma unroll
    for (int i = 0; i < 8; ++i) part += hq[i] * w2r[i];
    part = allred(part);
    if (lane == 0){
      s2s[q] = part;
      qms[q] = (qtok[b * Qq + q] != 0) ? 1.f : 0.f;
    }
  }
  __syncthreads();

  for (int p = pc * 100 + wid; p < pc * 100 + 100; p += 8){
    const float* hprow = Hp + ((size_t)b * Pp + p) * Dd + lane * 8;
    float4 hv0 = *(const float4*)hprow;
    float4 hv1 = *(const float4*)(hprow + 4);
    float hpc[8] = {hv0.x, hv0.y, hv0.z, hv0.w, hv1.x, hv1.y, hv1.z, hv1.w};
    float hw3[8], he3[8];
    float s1 = 0.f, ed = 0.f;
    #pragma unroll
    for (int i = 0; i < 8; ++i){
      hw3[i] = hpc[i] * w3r[i];
      he3[i] = hpc[i] * e3r[i];
      s1 += hpc[i] * w1r[i];
      ed += hpc[i] * e1r[i];
    }
    #pragma unroll
    for (int off = 1; off < 64; off <<= 1){
      s1 += __shfl_xor(s1, off);
      ed += __shfl_xor(ed, off);
    }
    for (int q = 0; q < Qq; ++q){
      const float4* hq4 = (const float4*)(hqs + q * Dd + lane * 8);
      float4 a0 = hq4[0], a1 = hq4[1];
      float dot = hw3[0] * a0.x + hw3[1] * a0.y + hw3[2] * a0.z + hw3[3] * a0.w
                + hw3[4] * a1.x + hw3[5] * a1.y + hw3[6] * a1.z + hw3[7] * a1.w;
      dot = allred(dot);
      if (lane == 0) scw[wid * 64 + q] = (s1 + s2s[q] + dot + sb) * qms[q];
    }
    float v = (lane < Qq) ? scw[wid * 64 + lane] : -1e30f;
    float M = allmax(v);
    float ev = (lane < Qq) ? expf(v - M) : 0.f;
    float S = allred(ev);
    float am = (lane < Qq) ? (ev / S) * qms[lane] : 0.f;
    float Sm = allred(am);
    float af = am / (Sm + 1e-13f);
    if (lane < Qq) aw[wid * 64 + lane] = af;
    float wv[8] = {0.f, 0.f, 0.f, 0.f, 0.f, 0.f, 0.f, 0.f};
    for (int q = 0; q < Qq; ++q){
      float aq = aw[wid * 64 + q];
      const float4* hq4 = (const float4*)(hqs + q * Dd + lane * 8);
      float4 a0 = hq4[0], a1 = hq4[1];
      wv[0] += aq * a0.x; wv[1] += aq * a0.y; wv[2] += aq * a0.z; wv[3] += aq * a0.w;
      wv[4] += aq * a1.x; wv[5] += aq * a1.y; wv[6] += aq * a1.z; wv[7] += aq * a1.w;
    }
    float acc2 = 0.f, acc3 = 0.f, acc4 = 0.f, acc5 = 0.f;
    #pragma unroll
    for (int i = 0; i < 8; ++i){
      acc2 += wv[i] * w2r[i];
      acc3 += hw3[i] * wv[i];
      acc4 += wv[i] * e2r[i];
      acc5 += he3[i] * wv[i];
    }
    #pragma unroll
    for (int off = 1; off < 64; off <<= 1){
      acc2 += __shfl_xor(acc2, off);
      acc3 += __shfl_xor(acc3, off);
      acc4 += __shfl_xor(acc4, off);
      acc5 += __shfl_xor(acc5, off);
    }
    if (lane == 0){
      bool pm = (ptok[b * Pp + p] != 0);
      out[(size_t)b * Pp + p]                = pm ? (s1 + acc2 + acc3 + sb) : NEGC;
      out[(size_t)Bb * Pp + (size_t)b * Pp + p] = pm ? (ed + acc4 + acc5 + eb) : NEGC;
    }
  }
}

// ---------------------------------------------------------------------------
// log_softmax over p (unchanged)
// ---------------------------------------------------------------------------
__global__ __launch_bounds__(512) void lsm_kernel(const int* __restrict__ ptok,
                                                  float* __restrict__ out){
  int b = blockIdx.x >> 1, sel = blockIdx.x & 1;
  const float* lg = out + (size_t)sel * Bb * Pp + (size_t)b * Pp;
  float* o = out + (size_t)(2 + sel) * Bb * Pp + (size_t)b * Pp;
  int tid = threadIdx.x;
  __shared__ float red1[8];
  __shared__ float red2[8];
  float x = -1e30f;
  if (tid < Pp) x = lg[tid] + ((ptok[b * Pp + tid] != 0) ? 0.f : LOGTINY);
  float m = allmax(x);
  if ((tid & 63) == 0) red1[tid >> 6] = m;
  __syncthreads();
  float M = red1[0];
  #pragma unroll
  for (int i = 1; i < 8; ++i) M = fmaxf(M, red1[i]);
  float e = (tid < Pp) ? expf(x - M) : 0.f;
  float s = allred(e);
  if ((tid & 63) == 0) red2[tid >> 6] = s;
  __syncthreads();
  float S = 0.f;
  #pragma unroll
  for (int i = 0; i < 8; ++i) S += red2[i];
  if (tid < Pp) o[tid] = (x - M) - logf(S);
}

// ---------------------------------------------------------------------------
extern "C" void kernel_launch(void* const* d_in, const int* in_sizes, int n_in,
                              void* d_out, int out_size, void* d_ws, size_t ws_size,
                              hipStream_t stream){
  const int*   passage  = (const int*)d_in[0];
  const int*   question = (const int*)d_in[1];
  const float* emb      = (const float*)d_in[2];
  const float* pW_ih    = (const float*)d_in[3];
  const float* pW_hh    = (const float*)d_in[4];
  const float* pb_ih    = (const float*)d_in[5];
  const float* pb_hh    = (const float*)d_in[6];
  const float* qW_ih    = (const float*)d_in[7];
  const float* qW_hh    = (const float*)d_in[8];
  const float* qb_ih    = (const float*)d_in[9];
  const float* qb_hh    = (const float*)d_in[10];
  const float* start_w  = (const float*)d_in[11];
  const float* start_b  = (const float*)d_in[12];
  const float* end_w    = (const float*)d_in[13];
  const float* end_b    = (const float*)d_in[14];
  float* out = (float*)d_out;

  // workspace layout (float-sized units)
  float*    ws   = (float*)d_ws;
  float*    wihT = ws;                         //   921600 : [g][d][e][h]
  unsigned* w16  = (unsigned*)(ws + 921600);   //   393216 u32 : packed fp16 Whh
  float*    xpp  = ws + 1314816;               // 39321600 : [d][b][t][768]
  float*    xpq  = ws + 40636416;              //  4915200
  float*    Hp   = ws + 45551616;              // 13107200 : [b][t][512]
  float*    Hq   = ws + 58658816;              //  1638400
  // total 60,297,216 floats = 241.2 MB

  hipLaunchKernelGGL(prep_wih, dim3(3600), dim3(256), 0, stream, pW_ih, qW_ih, wihT);
  hipLaunchKernelGGL(prep_w16, dim3(1536), dim3(256), 0, stream, pW_hh, qW_hh, w16);
  hipLaunchKernelGGL(xproj_gemm, dim3(24, 400), dim3(256), 0, stream,
                     passage, emb, wihT, pb_ih, xpp, Pp);
  hipLaunchKernelGGL(xproj_gemm, dim3(24, 50), dim3(256), 0, stream,
                     question, emb, wihT + 460800, qb_ih, xpq, Qq);
  hipLaunchKernelGGL(gru_kernel, dim3(256), dim3(768), 0, stream,
                     passage, question, xpp, xpq, w16, pb_hh, qb_hh, Hp, Hq);
  size_t attn_lds = (size_t)(Qq * Dd + 64 + 64 + 512 + 512) * sizeof(float);
  hipLaunchKernelGGL(attn_kernel, dim3(4, 64), dim3(512), attn_lds, stream,
                     Hp, Hq, passage, question, start_w, start_b, end_w, end_b, out);
  hipLaunchKernelGGL(lsm_kernel, dim3(128), dim3(512), 0, stream, passage, out);
}

// Round 3
// 1301.164 us; speedup vs baseline: 2.4613x; 1.2143x over previous
//
#include <hip/hip_runtime.h>
#include <math.h>

// Problem constants
constexpr int Bb = 64;    // batch
constexpr int Pp = 400;   // passage len
constexpr int Qq = 50;    // question len
constexpr int Ee = 300;   // embed dim
constexpr int Hh = 256;   // hidden
constexpr int H3 = 768;   // 3*H
constexpr int Dd = 512;   // 2*H

#define NEGC (-10000000.0f)
#define LOGTINY (-103.278929903f)   // log(float32(1e-45)) = log(2^-149)

typedef _Float16 h2 __attribute__((ext_vector_type(2)));
typedef _Float16 f16x8 __attribute__((ext_vector_type(8)));
typedef float f32x4 __attribute__((ext_vector_type(4)));

__device__ __forceinline__ float allred(float v){
  #pragma unroll
  for (int off = 1; off < 64; off <<= 1) v += __shfl_xor(v, off);
  return v;
}
__device__ __forceinline__ float allmax(float v){
  #pragma unroll
  for (int off = 1; off < 64; off <<= 1) v = fmaxf(v, __shfl_xor(v, off));
  return v;
}
__device__ __forceinline__ float sigm(float x){ return 1.f / (1.f + expf(-x)); }

__device__ __forceinline__ float dot2f(unsigned a, unsigned b, float c){
#if __has_builtin(__builtin_amdgcn_fdot2)
  return __builtin_amdgcn_fdot2(__builtin_bit_cast(h2, a), __builtin_bit_cast(h2, b), c, false);
#else
  float r = c;
  asm("v_dot2_f32_f16 %0, %1, %2, %0" : "+v"(r) : "v"(a), "s"(b));
  return r;
#endif
}

// ---------------------------------------------------------------------------
// Pack Whh to fp16 pairs, laid out so the GRU kernel's uint4 loads coalesce:
// w16[ (((g*2+d)*32 + q)*768 + j)*4 + c ] = pack(W[d][j][2p], W[d][j][2p+1]),
// with pair p = 4q + c.
// ---------------------------------------------------------------------------
__global__ __launch_bounds__(256) void prep_w16(const float* __restrict__ pW,
                                                const float* __restrict__ qW,
                                                unsigned* __restrict__ w16){
  int idx = blockIdx.x * 256 + threadIdx.x;   // pair id
  if (idx >= 2 * 2 * 128 * H3) return;
  int j = idx % H3; int r = idx / H3;
  int p = r % 128; r /= 128;
  int d = r & 1; int g = r >> 1;
  const float* W = g ? qW : pW;
  float w0 = W[((size_t)d * H3 + j) * Hh + 2 * p];
  float w1 = W[((size_t)d * H3 + j) * Hh + 2 * p + 1];
  _Float16 a = (_Float16)w0, b = (_Float16)w1;
  unsigned short ua, ub;
  __builtin_memcpy(&ua, &a, 2); __builtin_memcpy(&ub, &b, 2);
  unsigned out = (unsigned)ua | ((unsigned)ub << 16);
  w16[(((size_t)(g * 2 + d) * 32 + (p >> 2)) * H3 + j) * 4 + (p & 3)] = out;
}

// ---------------------------------------------------------------------------
// xproj via MFMA (fp16 in, fp32 acc): out[d][b][t][h] = emb[tok] @ Wih^T + b.
// A: gathered emb rows (M x 300), B: Wih[d][h][e] (n-major, k=e). Tile
// 128x128, BK=64, 8 waves (2Mx4N), each wave 64x32 = 4x2 tiles 16x16.
// ---------------------------------------------------------------------------
__global__ __launch_bounds__(512) void xproj_mfma(const int* __restrict__ tok,
                                                  const float* __restrict__ emb,
                                                  const float* __restrict__ Wih,
                                                  const float* __restrict__ bih,
                                                  float* __restrict__ xp, int T){
  __shared__ __align__(16) _Float16 As[128][72];
  __shared__ __align__(16) _Float16 Bs[128][72];
  int tid = threadIdx.x;
  int m0 = blockIdx.y * 128;
  int nt = blockIdx.x;                 // 0..11
  int d = nt / 6, h0 = (nt % 6) * 128;
  int wid = tid >> 6, lane = tid & 63;
  int wr = wid >> 2, wc = wid & 3;

  int srow = tid >> 2;                 // 0..127
  int scol = (tid & 3) * 16;           // 0,16,32,48
  const float* aRow = emb + (size_t)tok[m0 + srow] * Ee;
  const float* bRow = Wih + ((size_t)d * H3 + h0 + srow) * Ee;

  f32x4 acc[4][2] = {};

  for (int k0 = 0; k0 < 320; k0 += 64){
    // stage A and B (fp32 -> fp16), zero-pad k >= 300
    #pragma unroll
    for (int half = 0; half < 2; ++half){
      int k = k0 + scol + half * 8;
      float4 va0, va1, vb0, vb1;
      if (k + 8 <= Ee){
        va0 = *(const float4*)(aRow + k); va1 = *(const float4*)(aRow + k + 4);
        vb0 = *(const float4*)(bRow + k); vb1 = *(const float4*)(bRow + k + 4);
      } else if (k + 4 <= Ee){
        va0 = *(const float4*)(aRow + k); va1 = make_float4(0.f, 0.f, 0.f, 0.f);
        vb0 = *(const float4*)(bRow + k); vb1 = make_float4(0.f, 0.f, 0.f, 0.f);
      } else {
        va0 = va1 = vb0 = vb1 = make_float4(0.f, 0.f, 0.f, 0.f);
      }
      f16x8 a8 = { (_Float16)va0.x, (_Float16)va0.y, (_Float16)va0.z, (_Float16)va0.w,
                   (_Float16)va1.x, (_Float16)va1.y, (_Float16)va1.z, (_Float16)va1.w };
      f16x8 b8 = { (_Float16)vb0.x, (_Float16)vb0.y, (_Float16)vb0.z, (_Float16)vb0.w,
                   (_Float16)vb1.x, (_Float16)vb1.y, (_Float16)vb1.z, (_Float16)vb1.w };
      *(f16x8*)&As[srow][scol + half * 8] = a8;
      *(f16x8*)&Bs[srow][scol + half * 8] = b8;
    }
    __syncthreads();
    #pragma unroll
    for (int kc = 0; kc < 2; ++kc){
      int kb = kc * 32 + (lane >> 4) * 8;
      f16x8 af[4], bf[2];
      #pragma unroll
      for (int i = 0; i < 4; ++i) af[i] = *(const f16x8*)&As[wr * 64 + i * 16 + (lane & 15)][kb];
      #pragma unroll
      for (int jn = 0; jn < 2; ++jn) bf[jn] = *(const f16x8*)&Bs[wc * 32 + jn * 16 + (lane & 15)][kb];
      #pragma unroll
      for (int i = 0; i < 4; ++i)
        #pragma unroll
        for (int jn = 0; jn < 2; ++jn)
          acc[i][jn] = __builtin_amdgcn_mfma_f32_16x16x32_f16(af[i], bf[jn], acc[i][jn], 0, 0, 0);
    }
    __syncthreads();
  }

  // epilogue: add bias, scatter (C/D layout: col=lane&15, row=(lane>>4)*4+reg)
  #pragma unroll
  for (int jn = 0; jn < 2; ++jn){
    int h = h0 + wc * 32 + jn * 16 + (lane & 15);
    float bv = bih[d * H3 + h];
    #pragma unroll
    for (int i = 0; i < 4; ++i){
      #pragma unroll
      for (int r = 0; r < 4; ++r){
        int m = m0 + wr * 64 + i * 16 + (lane >> 4) * 4 + r;
        int bI = m / T, tI = m - bI * T;
        xp[(((size_t)d * Bb + bI) * T + tI) * H3 + h] = acc[i][jn][r] + bv;
      }
    }
  }
}

// ---------------------------------------------------------------------------
// Register-resident GRU. One WG per (seq-kind, dir, batch): 256 WGs x 768 thr,
// 3 waves/EU (launch_bounds cap 170 VGPR -> w[128] stays in registers).
// Thread j holds Whh row j as 128 packed fp16-pair VGPRs. Per step: packed
// fp16 h from LDS (2 x b32) -> readlane broadcast + v_dot2_f32_f16.
// Gates on threads 512..767 (x_n, hp_n already local).
// ---------------------------------------------------------------------------
__global__ __launch_bounds__(768, 3) void gru_kernel(const int* __restrict__ ptok,
                                                     const int* __restrict__ qtok,
                                                     const float* __restrict__ xpp,
                                                     const float* __restrict__ xpq,
                                                     const unsigned* __restrict__ w16,
                                                     const float* __restrict__ pbhh,
                                                     const float* __restrict__ qbhh,
                                                     float* __restrict__ Hp,
                                                     float* __restrict__ Hq){
  int wg = blockIdx.x;
  bool isp = wg < 128;
  int lw = isp ? wg : wg - 128;
  int d = lw & 1, b = lw >> 1;
  int T = isp ? Pp : Qq;
  const int* tok = (isp ? ptok : qtok) + b * T;
  const float* xrow = (isp ? xpp : xpq) + ((size_t)d * Bb + b) * T * H3;
  int gd = (isp ? 0 : 2) + d;
  const float* bhh = (isp ? pbhh : qbhh) + d * H3;
  float* Hout = (isp ? Hp : Hq) + (size_t)b * T * Dd + d * Hh;

  __shared__ __align__(4) _Float16 hs16[Hh];
  __shared__ float us[2 * Hh];

  int j = threadIdx.x;
  unsigned w[128];
  {
    const uint4* wq = (const uint4*)w16 + (size_t)gd * 32 * H3;
    #pragma unroll
    for (int q = 0; q < 32; ++q){
      uint4 v = wq[q * H3 + j];
      w[4 * q + 0] = v.x; w[4 * q + 1] = v.y; w[4 * q + 2] = v.z; w[4 * q + 3] = v.w;
    }
  }
  float bh = bhh[j];
  float h_old = 0.f;
  if (j < Hh) hs16[j] = (_Float16)0.f;
  __syncthreads();

  int lane = j & 63;
  float pre = xrow[(size_t)(d ? (T - 1) : 0) * H3 + j];

  for (int s = 0; s < T; ++s){
    int t = d ? (T - 1 - s) : s;
    float xt = pre;
    if (s + 1 < T) pre = xrow[(size_t)(d ? (T - 2 - s) : (s + 1)) * H3 + j];

    unsigned vh0 = *(const unsigned*)&hs16[2 * lane];
    unsigned vh1 = *(const unsigned*)&hs16[128 + 2 * lane];

    float acc0 = bh, acc1 = 0.f;
    #pragma unroll
    for (int q = 0; q < 32; ++q){
      #define RL(p) ((unsigned)__builtin_amdgcn_readlane((int)(((p) < 64) ? vh0 : vh1), (p) & 63))
      acc0 = dot2f(w[4 * q + 0], RL(4 * q + 0), acc0);
      acc1 = dot2f(w[4 * q + 1], RL(4 * q + 1), acc1);
      acc0 = dot2f(w[4 * q + 2], RL(4 * q + 2), acc0);
      acc1 = dot2f(w[4 * q + 3], RL(4 * q + 3), acc1);
      #undef RL
    }
    float acc = acc0 + acc1;
    if (j < 2 * Hh) us[j] = xt + acc;
    __syncthreads();
    if (j >= 2 * Hh){
      int jj = j - 2 * Hh;
      float r = sigm(us[jj]);
      float z = sigm(us[Hh + jj]);
      float n = tanhf(xt + r * acc);
      float hnew = (1.f - z) * n + z * h_old;
      float m = (tok[t] != 0) ? 1.f : 0.f;
      float hm = m * hnew + (1.f - m) * h_old;
      h_old = hm;
      hs16[jj] = (_Float16)hm;
      Hout[(size_t)t * Dd + jj] = hm * m;
    }
    __syncthreads();
  }
}

// ---------------------------------------------------------------------------
// Attention + logits (unchanged)
// ---------------------------------------------------------------------------
__global__ __launch_bounds__(512) void attn_kernel(const float* __restrict__ Hp,
                                                   const float* __restrict__ Hq,
                                                   const int* __restrict__ ptok,
                                                   const int* __restrict__ qtok,
                                                   const float* __restrict__ start_w,
                                                   const float* __restrict__ sbp,
                                                   const float* __restrict__ end_w,
                                                   const float* __restrict__ ebp,
                                                   float* __restrict__ out){
  extern __shared__ __align__(16) float lds[];
  float* hqs = lds;               // 50*512
  float* s2s = hqs + Qq * Dd;     // 64
  float* qms = s2s + 64;          // 64
  float* scw = qms + 64;          // 8*64
  float* aw  = scw + 512;         // 8*64

  int b = blockIdx.y, pc = blockIdx.x;
  int tid = threadIdx.x, wid = tid >> 6, lane = tid & 63;
  float sb = sbp[0], eb = ebp[0];

  float w1r[8], w2r[8], w3r[8], e1r[8], e2r[8], e3r[8];
  #pragma unroll
  for (int i = 0; i < 8; ++i){
    int c = lane * 8 + i;
    w1r[i] = start_w[c]; w2r[i] = start_w[Dd + c]; w3r[i] = start_w[2 * Dd + c];
    e1r[i] = end_w[c];   e2r[i] = end_w[Dd + c];   e3r[i] = end_w[2 * Dd + c];
  }
  for (int idx = tid; idx < Qq * Dd; idx += 512) hqs[idx] = Hq[(size_t)b * Qq * Dd + idx];
  __syncthreads();

  for (int q = wid; q < Qq; q += 8){
    float part = 0.f;
    const float* hq = hqs + q * Dd + lane * 8;
    #pragma unroll
    for (int i = 0; i < 8; ++i) part += hq[i] * w2r[i];
    part = allred(part);
    if (lane == 0){
      s2s[q] = part;
      qms[q] = (qtok[b * Qq + q] != 0) ? 1.f : 0.f;
    }
  }
  __syncthreads();

  for (int p = pc * 100 + wid; p < pc * 100 + 100; p += 8){
    const float* hprow = Hp + ((size_t)b * Pp + p) * Dd + lane * 8;
    float4 hv0 = *(const float4*)hprow;
    float4 hv1 = *(const float4*)(hprow + 4);
    float hpc[8] = {hv0.x, hv0.y, hv0.z, hv0.w, hv1.x, hv1.y, hv1.z, hv1.w};
    float hw3[8], he3[8];
    float s1 = 0.f, ed = 0.f;
    #pragma unroll
    for (int i = 0; i < 8; ++i){
      hw3[i] = hpc[i] * w3r[i];
      he3[i] = hpc[i] * e3r[i];
      s1 += hpc[i] * w1r[i];
      ed += hpc[i] * e1r[i];
    }
    #pragma unroll
    for (int off = 1; off < 64; off <<= 1){
      s1 += __shfl_xor(s1, off);
      ed += __shfl_xor(ed, off);
    }
    for (int q = 0; q < Qq; ++q){
      const float4* hq4 = (const float4*)(hqs + q * Dd + lane * 8);
      float4 a0 = hq4[0], a1 = hq4[1];
      float dot = hw3[0] * a0.x + hw3[1] * a0.y + hw3[2] * a0.z + hw3[3] * a0.w
                + hw3[4] * a1.x + hw3[5] * a1.y + hw3[6] * a1.z + hw3[7] * a1.w;
      dot = allred(dot);
      if (lane == 0) scw[wid * 64 + q] = (s1 + s2s[q] + dot + sb) * qms[q];
    }
    float v = (lane < Qq) ? scw[wid * 64 + lane] : -1e30f;
    float M = allmax(v);
    float ev = (lane < Qq) ? expf(v - M) : 0.f;
    float S = allred(ev);
    float am = (lane < Qq) ? (ev / S) * qms[lane] : 0.f;
    float Sm = allred(am);
    float af = am / (Sm + 1e-13f);
    if (lane < Qq) aw[wid * 64 + lane] = af;
    float wv[8] = {0.f, 0.f, 0.f, 0.f, 0.f, 0.f, 0.f, 0.f};
    for (int q = 0; q < Qq; ++q){
      float aq = aw[wid * 64 + q];
      const float4* hq4 = (const float4*)(hqs + q * Dd + lane * 8);
      float4 a0 = hq4[0], a1 = hq4[1];
      wv[0] += aq * a0.x; wv[1] += aq * a0.y; wv[2] += aq * a0.z; wv[3] += aq * a0.w;
      wv[4] += aq * a1.x; wv[5] += aq * a1.y; wv[6] += aq * a1.z; wv[7] += aq * a1.w;
    }
    float acc2 = 0.f, acc3 = 0.f, acc4 = 0.f, acc5 = 0.f;
    #pragma unroll
    for (int i = 0; i < 8; ++i){
      acc2 += wv[i] * w2r[i];
      acc3 += hw3[i] * wv[i];
      acc4 += wv[i] * e2r[i];
      acc5 += he3[i] * wv[i];
    }
    #pragma unroll
    for (int off = 1; off < 64; off <<= 1){
      acc2 += __shfl_xor(acc2, off);
      acc3 += __shfl_xor(acc3, off);
      acc4 += __shfl_xor(acc4, off);
      acc5 += __shfl_xor(acc5, off);
    }
    if (lane == 0){
      bool pm = (ptok[b * Pp + p] != 0);
      out[(size_t)b * Pp + p]                   = pm ? (s1 + acc2 + acc3 + sb) : NEGC;
      out[(size_t)Bb * Pp + (size_t)b * Pp + p] = pm ? (ed + acc4 + acc5 + eb) : NEGC;
    }
  }
}

// ---------------------------------------------------------------------------
// log_softmax over p (unchanged)
// ---------------------------------------------------------------------------
__global__ __launch_bounds__(512) void lsm_kernel(const int* __restrict__ ptok,
                                                  float* __restrict__ out){
  int b = blockIdx.x >> 1, sel = blockIdx.x & 1;
  const float* lg = out + (size_t)sel * Bb * Pp + (size_t)b * Pp;
  float* o = out + (size_t)(2 + sel) * Bb * Pp + (size_t)b * Pp;
  int tid = threadIdx.x;
  __shared__ float red1[8];
  __shared__ float red2[8];
  float x = -1e30f;
  if (tid < Pp) x = lg[tid] + ((ptok[b * Pp + tid] != 0) ? 0.f : LOGTINY);
  float m = allmax(x);
  if ((tid & 63) == 0) red1[tid >> 6] = m;
  __syncthreads();
  float M = red1[0];
  #pragma unroll
  for (int i = 1; i < 8; ++i) M = fmaxf(M, red1[i]);
  float e = (tid < Pp) ? expf(x - M) : 0.f;
  float s = allred(e);
  if ((tid & 63) == 0) red2[tid >> 6] = s;
  __syncthreads();
  float S = 0.f;
  #pragma unroll
  for (int i = 0; i < 8; ++i) S += red2[i];
  if (tid < Pp) o[tid] = (x - M) - logf(S);
}

// ---------------------------------------------------------------------------
extern "C" void kernel_launch(void* const* d_in, const int* in_sizes, int n_in,
                              void* d_out, int out_size, void* d_ws, size_t ws_size,
                              hipStream_t stream){
  const int*   passage  = (const int*)d_in[0];
  const int*   question = (const int*)d_in[1];
  const float* emb      = (const float*)d_in[2];
  const float* pW_ih    = (const float*)d_in[3];
  const float* pW_hh    = (const float*)d_in[4];
  const float* pb_ih    = (const float*)d_in[5];
  const float* pb_hh    = (const float*)d_in[6];
  const float* qW_ih    = (const float*)d_in[7];
  const float* qW_hh    = (const float*)d_in[8];
  const float* qb_ih    = (const float*)d_in[9];
  const float* qb_hh    = (const float*)d_in[10];
  const float* start_w  = (const float*)d_in[11];
  const float* start_b  = (const float*)d_in[12];
  const float* end_w    = (const float*)d_in[13];
  const float* end_b    = (const float*)d_in[14];
  float* out = (float*)d_out;

  // workspace layout (float-sized units)
  float*    ws  = (float*)d_ws;
  unsigned* w16 = (unsigned*)ws;            //   393216 u32 : packed fp16 Whh
  float*    xpp = ws + 393216;              // 39321600 : [d][b][t][768]
  float*    xpq = ws + 39714816;            //  4915200
  float*    Hp  = ws + 44630016;            // 13107200 : [b][t][512]
  float*    Hq  = ws + 57737216;            //  1638400
  // total 59,375,616 floats = 237.5 MB

  hipLaunchKernelGGL(prep_w16, dim3(1536), dim3(256), 0, stream, pW_hh, qW_hh, w16);
  hipLaunchKernelGGL(xproj_mfma, dim3(12, 200), dim3(512), 0, stream,
                     passage, emb, pW_ih, pb_ih, xpp, Pp);
  hipLaunchKernelGGL(xproj_mfma, dim3(12, 25), dim3(512), 0, stream,
                     question, emb, qW_ih, qb_ih, xpq, Qq);
  hipLaunchKernelGGL(gru_kernel, dim3(256), dim3(768), 0, stream,
                     passage, question, xpp, xpq, w16, pb_hh, qb_hh, Hp, Hq);
  size_t attn_lds = (size_t)(Qq * Dd + 64 + 64 + 512 + 512) * sizeof(float);
  hipLaunchKernelGGL(attn_kernel, dim3(4, 64), dim3(512), attn_lds, stream,
                     Hp, Hq, passage, question, start_w, start_b, end_w, end_b, out);
  hipLaunchKernelGGL(lsm_kernel, dim3(128), dim3(512), 0, stream, passage, out);
}